// Round 2
// baseline (4239.482 us; speedup 1.0000x reference)
//
#include <hip/hip_runtime.h>
#include <math.h>

#define B_ 16
#define N_ 256
#define L_ 32
#define NN_ (N_*N_)          // 65536
#define NNL_ (NN_*L_)        // 2097152 elements per batch
#define ANN_ (B_*NN_)        // 1048576
#define POTS_OFF 4096        // float offset where big arrays start
#define NEGINF -1.0e30f
#define LOG2E_F 1.4426950408889634f
#define LN2_F   0.6931471805599453f

// Fast base-2 transcendentals: v_exp_f32 / v_log_f32 directly.
#if __has_builtin(__builtin_amdgcn_exp2f)
#define EX2(x) __builtin_amdgcn_exp2f(x)
#else
#define EX2(x) exp2f(x)
#endif
#if __has_builtin(__builtin_amdgcn_logf)
#define LG2(x) __builtin_amdgcn_logf(x)
#else
#define LG2(x) log2f(x)
#endif

// Drain all outstanding VMEM ops (stores included) and forbid the compiler
// from moving memory ops across. One wave per chain means chart row w written
// at step w is read at step w+1 by the SAME wave: hardware does NOT guarantee
// store->load ordering for in-flight VMEM, so drain once per width step.
#define VMEM_FENCE() asm volatile("s_waitcnt vmcnt(0)" ::: "memory")

// ws float layout (float* W = (float*)d_ws):
//   [0 .. 2048)  : 1024 doubles — stats partials [B][32][2]
//   [2048..2080) : stats (mean, invstd) per batch
//   W + POTS_OFF + k*ANN_:
//     0: pot1 (width-major, log2 units)   1: sbar (width-major, nat units)
//     2: pot2 (log2)   3: pot3 (log2)
//     4-5: SW_p0 (float2 (ev,h) chart, width-major)   6-7: EW_p0
//     8: SW_p1   9: EW_p1   10: SW_p2   11: EW_p2
//   W + POTS_OFF + 12*ANN_: zres[64]
//
// cky structure: ONE WAVE per (pass,batch) chain — 48 blocks x 64 threads.
// No __syncthreads in the width loop: cross-step ordering is wave-internal
// program order + one explicit vmcnt(0) drain per step. Width-major dual
// charts SW[w][i] / EW[w][j] make lane-per-cell loads coalesced.

// ---------------- kernel 1a: per-batch sum/sumsq partials ----------------
__global__ void stats_partial(const float* __restrict__ lp, double* __restrict__ part) {
    int blk = blockIdx.x;            // 0..511 = B*32
    int b = blk >> 5, seg = blk & 31;
    const float4* p4 = (const float4*)(lp + (size_t)b * NNL_ + (size_t)seg * (NNL_ / 32));
    double s = 0.0, ss = 0.0;
    for (int idx = threadIdx.x; idx < (NNL_ / 32 / 4); idx += 256) {
        float4 v = p4[idx];
        s  += (double)v.x + (double)v.y + (double)v.z + (double)v.w;
        ss += (double)v.x * v.x + (double)v.y * v.y + (double)v.z * v.z + (double)v.w * v.w;
    }
    __shared__ double sh0[256], sh1[256];
    sh0[threadIdx.x] = s; sh1[threadIdx.x] = ss;
    __syncthreads();
    for (int off = 128; off > 0; off >>= 1) {
        if (threadIdx.x < off) {
            sh0[threadIdx.x] += sh0[threadIdx.x + off];
            sh1[threadIdx.x] += sh1[threadIdx.x + off];
        }
        __syncthreads();
    }
    if (threadIdx.x == 0) { part[blk * 2] = sh0[0]; part[blk * 2 + 1] = sh1[0]; }
}

// ---------------- kernel 1b: finalize mean/invstd ----------------
__global__ void stats_final(const double* __restrict__ part, float* __restrict__ stats) {
    int b = threadIdx.x;
    if (b >= B_) return;
    double s = 0.0, ss = 0.0;
    for (int k = 0; k < 32; ++k) { s += part[(b * 32 + k) * 2]; ss += part[(b * 32 + k) * 2 + 1]; }
    double n = (double)NNL_;
    double mean = s / n;
    double var = (ss - s * s / n) / (n - 1.0);
    stats[b * 2]     = (float)mean;
    stats[b * 2 + 1] = (float)(1.0 / sqrt(var));
}

// ---------------- kernel 2: label-lse -> span potentials (thread/cell) -------
// One THREAD per cell; outputs WIDTH-MAJOR (pot[w*N+i]) and pot values in
// log2 units (sbar stays nat: it's an expectation of x, not a log-potential).
__global__ __launch_bounds__(256)
void pots_kernel(const float* __restrict__ lp, const float* __restrict__ evm,
                 const float* __restrict__ stats, float* __restrict__ W) {
    int t = blockIdx.x * 256 + threadIdx.x;     // 0 .. B*NN-1
    int b = t >> 16;
    int rem = t & (NN_ - 1);
    int i = rem >> 8;
    int w = rem & (N_ - 1);
    if (i + w >= N_) return;
    int j = i + w;
    const float4* xp = (const float4*)(lp  + ((size_t)(b * NN_ + i * N_ + j) << 5));
    const float4* ep = (const float4*)(evm + ((size_t)(b * NN_ + i * N_ + j) << 5));
    float mean = stats[b * 2], invstd = stats[b * 2 + 1];
    float m1 = NEGINF, s1 = 0.f, n1 = 0.f;
    float m2 = NEGINF, s2 = 0.f;
    float m3 = NEGINF, s3 = 0.f;
#pragma unroll
    for (int c = 0; c < 8; ++c) {
        float4 xv = xp[c];
        float4 em = ep[c];
        float x0 = (xv.x - mean) * invstd, x1 = (xv.y - mean) * invstd;
        float x2 = (xv.z - mean) * invstd, x3 = (xv.w - mean) * invstd;
        {
            float cm = fmaxf(fmaxf(x0, x1), fmaxf(x2, x3));
            float nm = fmaxf(m1, cm);
            float sc = __expf(m1 - nm);
            float e0 = __expf(x0 - nm), e1 = __expf(x1 - nm);
            float e2 = __expf(x2 - nm), e3 = __expf(x3 - nm);
            s1 = s1 * sc + (e0 + e1 + e2 + e3);
            n1 = n1 * sc + (e0 * x0 + e1 * x1 + e2 * x2 + e3 * x3);
            m1 = nm;
        }
        {
            float y0 = x0 + __logf(fmaf(em.x, 0.9f, 0.1f) + 1e-10f);
            float y1 = x1 + __logf(fmaf(em.y, 0.9f, 0.1f) + 1e-10f);
            float y2 = x2 + __logf(fmaf(em.z, 0.9f, 0.1f) + 1e-10f);
            float y3 = x3 + __logf(fmaf(em.w, 0.9f, 0.1f) + 1e-10f);
            float cm = fmaxf(fmaxf(y0, y1), fmaxf(y2, y3));
            float nm = fmaxf(m2, cm);
            float sc = __expf(m2 - nm);
            s2 = s2 * sc + __expf(y0 - nm) + __expf(y1 - nm) + __expf(y2 - nm) + __expf(y3 - nm);
            m2 = nm;
        }
        {
            float z0 = fmaf(em.x, 1e6f, x0 - 1e6f);
            float z1 = fmaf(em.y, 1e6f, x1 - 1e6f);
            float z2 = fmaf(em.z, 1e6f, x2 - 1e6f);
            float z3 = fmaf(em.w, 1e6f, x3 - 1e6f);
            float cm = fmaxf(fmaxf(z0, z1), fmaxf(z2, z3));
            float nm = fmaxf(m3, cm);
            float sc = __expf(m3 - nm);
            s3 = s3 * sc + __expf(z0 - nm) + __expf(z1 - nm) + __expf(z2 - nm) + __expf(z3 - nm);
            m3 = nm;
        }
    }
    int o = b * NN_ + w * N_ + i;                // WIDTH-MAJOR layout
    W[POTS_OFF + 0 * ANN_ + o] = (m1 + __logf(s1)) * LOG2E_F;
    W[POTS_OFF + 1 * ANN_ + o] = n1 / s1;
    W[POTS_OFF + 2 * ANN_ + o] = (m2 + __logf(s2)) * LOG2E_F;
    W[POTS_OFF + 3 * ANN_ + o] = (m3 + __logf(s3)) * LOG2E_F;
}

// ---------------- chart element type: float2 (ev,h) for p0, float otherwise --
template <bool E> struct ElemS { using T = float2; };
template <> struct ElemS<false> { using T = float; };

__device__ __forceinline__ float evx(float v)  { return v; }
__device__ __forceinline__ float evx(float2 v) { return v.x; }
__device__ __forceinline__ float hy(float v)   { (void)v; return 0.f; }
__device__ __forceinline__ float hy(float2 v)  { return v.y; }

// ---------------- one width step, single wave --------------------------------
// NG = cells in flight per block-slot (low lane bits), G = 64/NG lanes per cell
// (high lane bits, strided over splits). Up to 4 block-slots accumulated
// simultaneously per lane -> 4 independent online-softmax chains + up to 32
// loads in flight = ILP-based latency hiding (there is no TLP: one wave/CU).
template <bool EXPM, int LOGNG>
__device__ __forceinline__ void stepk(const float* __restrict__ pot,
                                      const float* __restrict__ sbr,
                                      typename ElemS<EXPM>::T* __restrict__ SW,
                                      typename ElemS<EXPM>::T* __restrict__ EW,
                                      const int w, const int cells, const int lane)
{
    using T = typename ElemS<EXPM>::T;
    constexpr int NG = 1 << LOGNG;
    constexpr int G  = 64 >> LOGNG;
    constexpr int GN = G * N_;
    const int g = lane & (NG - 1);
    const int l = lane >> LOGNG;
    const int nb = (cells + NG - 1) >> LOGNG;   // 1..4

    const T* Lb = SW + l * N_ + g;              // SW[u][i],   u starts at l
    const T* Rb = EW + (w - 1 - l) * N_ + (g + w); // EW[w-1-u][i+w], descending

    float m[4], s[4], n[4];
#pragma unroll
    for (int blk = 0; blk < 4; ++blk) { m[blk] = NEGINF; s[blk] = 0.f; n[blk] = 0.f; }

    int u = l;
    // main chunks: 4 splits per lane per block-slot
    for (; u + 3 * G < w; u += 4 * G) {
#pragma unroll
        for (int blk = 0; blk < 4; ++blk) {
            if (blk < nb) {
                const int bo = blk << LOGNG;
                T L0 = Lb[bo], L1 = Lb[bo + GN], L2 = Lb[bo + 2 * GN], L3 = Lb[bo + 3 * GN];
                T R0 = Rb[bo], R1 = Rb[bo - GN], R2 = Rb[bo - 2 * GN], R3 = Rb[bo - 3 * GN];
                float e0 = evx(L0) + evx(R0), e1 = evx(L1) + evx(R1);
                float e2 = evx(L2) + evx(R2), e3 = evx(L3) + evx(R3);
                float cm = fmaxf(fmaxf(e0, e1), fmaxf(e2, e3));
                float nm = fmaxf(m[blk], cm);
                float sc = EX2(m[blk] - nm);
                float E0 = EX2(e0 - nm), E1 = EX2(e1 - nm);
                float E2 = EX2(e2 - nm), E3 = EX2(e3 - nm);
                s[blk] = s[blk] * sc + ((E0 + E1) + (E2 + E3));
                if constexpr (EXPM) {
                    float h0 = hy(L0) + hy(R0), h1 = hy(L1) + hy(R1);
                    float h2 = hy(L2) + hy(R2), h3 = hy(L3) + hy(R3);
                    n[blk] = n[blk] * sc + ((E0 * h0 + E1 * h1) + (E2 * h2 + E3 * h3));
                }
                m[blk] = nm;
            }
        }
        Lb += 4 * GN; Rb -= 4 * GN;
    }
    // remainder singles (<= 3 per lane)
    for (; u < w; u += G) {
#pragma unroll
        for (int blk = 0; blk < 4; ++blk) {
            if (blk < nb) {
                const int bo = blk << LOGNG;
                T L = Lb[bo], R = Rb[bo];
                float e = evx(L) + evx(R);
                float nm = fmaxf(m[blk], e);
                float sc = EX2(m[blk] - nm), E = EX2(e - nm);
                s[blk] = s[blk] * sc + E;
                if constexpr (EXPM) n[blk] = n[blk] * sc + E * (hy(L) + hy(R));
                m[blk] = nm;
            }
        }
        Lb += GN; Rb -= GN;
    }

    // merge the G split-partials across the high lane bits
    if constexpr (NG < 64) {
#pragma unroll
        for (int blk = 0; blk < 4; ++blk) {
            if (blk < nb) {
#pragma unroll
                for (int k = NG; k <= 32; k <<= 1) {
                    float mo = __shfl_xor(m[blk], k);
                    float so = __shfl_xor(s[blk], k);
                    float nm = fmaxf(m[blk], mo);
                    float a = EX2(m[blk] - nm), bsc = EX2(mo - nm);
                    s[blk] = s[blk] * a + so * bsc;
                    if constexpr (EXPM) {
                        float no = __shfl_xor(n[blk], k);
                        n[blk] = n[blk] * a + no * bsc;
                    }
                    m[blk] = nm;
                }
            }
        }
    }

    float vres[4], hres[4];
#pragma unroll
    for (int blk = 0; blk < 4; ++blk) {
        vres[blk] = 0.f; hres[blk] = 0.f;
        if (blk < nb) {
            const int i = (blk << LOGNG) + g;
            vres[blk] = pot[w * N_ + i] + m[blk] + LG2(s[blk]);
            if constexpr (EXPM) hres[blk] = sbr[w * N_ + i] + n[blk] / s[blk];
        }
    }
    // all stores clustered at the end -> single drain point at next step
#pragma unroll
    for (int blk = 0; blk < 4; ++blk) {
        if (blk < nb) {
            const int i = (blk << LOGNG) + g;
            if (l == 0 && i < cells) {
                if constexpr (EXPM) {
                    float2 val; val.x = vres[blk]; val.y = hres[blk];
                    SW[w * N_ + i] = val;
                    EW[w * N_ + i + w] = val;
                } else {
                    SW[w * N_ + i] = vres[blk];
                    EW[w * N_ + i + w] = vres[blk];
                }
            }
        }
    }
}

template <bool EXPM>
__device__ __forceinline__ void cky_chain(const float* __restrict__ pot,
                                          const float* __restrict__ sbr,
                                          typename ElemS<EXPM>::T* __restrict__ SW,
                                          typename ElemS<EXPM>::T* __restrict__ EW,
                                          const int len, const int lane)
{
    using T = typename ElemS<EXPM>::T;
    // width-0 diagonal
    for (int i = lane; i < len; i += 64) {
        T v;
        if constexpr (EXPM) { v.x = pot[i]; v.y = sbr[i]; }
        else v = pot[i];
        SW[i] = v;
        EW[i] = v;
    }
    for (int w = 1; w < len; ++w) {
        VMEM_FENCE();   // row w-1 stores must be visible before row w-1 reads
        const int cells = len - w;
        if (cells >= 64)      stepk<EXPM, 6>(pot, sbr, SW, EW, w, cells, lane);
        else if (cells >= 16) stepk<EXPM, 4>(pot, sbr, SW, EW, w, cells, lane);
        else                  stepk<EXPM, 2>(pot, sbr, SW, EW, w, cells, lane);
    }
    VMEM_FENCE();       // root store visible before readback
}

// ---------------- kernel 3: all three CKY inside passes, 1 wave/chain --------
__global__ __launch_bounds__(64)
void cky_all(float* __restrict__ W, const int* __restrict__ lengths) {
    const int bx = blockIdx.x;
    const int p = bx >> 4, b = bx & 15;
    const int lane = threadIdx.x;
    int len = lengths[b];
    if (len < 1) len = 1;
    if (len > N_) len = N_;
    float* zres = W + POTS_OFF + 12 * ANN_;

    if (p == 0) {
        const float* pot = W + POTS_OFF + 0 * ANN_ + b * NN_;
        const float* sbr = W + POTS_OFF + 1 * ANN_ + b * NN_;
        float2* SW = (float2*)(W + POTS_OFF + 4 * ANN_) + b * NN_;
        float2* EW = (float2*)(W + POTS_OFF + 6 * ANN_) + b * NN_;
        cky_chain<true>(pot, sbr, SW, EW, len, lane);
        if (lane == 0) {
            float2 r = SW[(len - 1) * N_];     // cell (0, len-1)
            zres[b]      = r.x;                // logZ_full (log2 units)
            zres[48 + b] = r.y;                // E[sum sbar] (nat units)
        }
    } else {
        const float* pot = W + POTS_OFF + (p == 1 ? 2 : 3) * ANN_ + b * NN_;
        float* SW = W + POTS_OFF + (p == 1 ? 8 : 10) * ANN_ + b * NN_;
        float* EW = W + POTS_OFF + (p == 1 ? 9 : 11) * ANN_ + b * NN_;
        cky_chain<false>(pot, pot, SW, EW, len, lane);
        if (lane == 0) zres[p * 16 + b] = SW[(len - 1) * N_];
    }
}

// ---------------- kernel 4: combine outputs ----------------
__global__ void combine_kernel(const float* __restrict__ W, float* __restrict__ out) {
    int b = threadIdx.x;
    if (b >= B_) return;
    const float* zres = W + POTS_OFF + 12 * ANN_;
    float zf = zres[b], zs = zres[16 + b], zp = zres[32 + b], hr = zres[48 + b];
    out[b]          = (zp - zf) * LN2_F;   // log_prob
    out[16 + b]     = (zs - zf) * LN2_F;   // log_prob_smooth
    out[32 + b]     = zf * LN2_F - hr;     // entropy = z_full - E[sum sbar]
}

extern "C" void kernel_launch(void* const* d_in, const int* in_sizes, int n_in,
                              void* d_out, int out_size, void* d_ws, size_t ws_size,
                              hipStream_t stream) {
    const float* lp      = (const float*)d_in[0];
    // d_in[1] (mask) is unused by the reference
    const int*   lengths = (const int*)d_in[2];
    const float* evm     = (const float*)d_in[3];
    float*  W    = (float*)d_ws;
    double* part = (double*)d_ws;
    float*  stats = W + 2048;
    float*  out  = (float*)d_out;

    stats_partial<<<B_ * 32, 256, 0, stream>>>(lp, part);
    stats_final<<<1, 64, 0, stream>>>(part, stats);
    pots_kernel<<<(B_ * NN_) / 256, 256, 0, stream>>>(lp, evm, stats, W);
    cky_all<<<3 * B_, 64, 0, stream>>>(W, lengths);
    combine_kernel<<<1, 64, 0, stream>>>(W, out);
}

// Round 3
// 907.741 us; speedup vs baseline: 4.6704x; 4.6704x over previous
//
#include <hip/hip_runtime.h>
#include <math.h>

#define B_ 16
#define N_ 256
#define L_ 32
#define NN_ (N_*N_)          // 65536
#define NNL_ (NN_*L_)        // 2097152 elements per batch
#define ANN_ (B_*NN_)        // 1048576
#define POTS_OFF 4096        // float offset where big arrays start
#define NEGINF -1.0e30f
#define LOG2E_F 1.4426950408889634f
#define LN2_F   0.6931471805599453f

// Fast base-2 transcendentals (v_exp_f32 / v_log_f32). Math verified in r2 run.
#if __has_builtin(__builtin_amdgcn_exp2f)
#define EX2(x) __builtin_amdgcn_exp2f(x)
#else
#define EX2(x) exp2f(x)
#endif
#if __has_builtin(__builtin_amdgcn_logf)
#define LG2(x) __builtin_amdgcn_logf(x)
#else
#define LG2(x) log2f(x)
#endif

// ws float layout (float* W = (float*)d_ws):
//   [0 .. 2048)  : 1024 doubles — stats partials [B][32][2]
//   [2048..2080) : stats (mean, invstd) per batch
//   W + POTS_OFF + k*ANN_:
//     0: pot1 (start-major, log2 units)   1: sbar (start-major, nat units)
//     2: pot2 (log2)   3: pot3 (log2)
//     4: EG_ev p0 (end-major chart)  5: EG_h p0  6: SG_h p0 (start-major h)
//     7: EG p1   8: EG p2
//   W + POTS_OFF + 9*ANN_: zres[64]
//
// cky structure (r2 post-mortem: 1-wave was latency-bound; TLP is mandatory):
// 48 blocks x 1024 threads (16 waves). LEFT operand chart lives in LDS
// (triangular start-major, granule-XOR swizzled, ds_read_b128 ~10cy);
// RIGHT operand from a global END-major chart where each cell's whole split
// run is one contiguous row (unaligned 16B loads, L2-resident, TLP-hidden).
// One __syncthreads per width step (compiler drains vmcnt+lgkmcnt there).

// ---------------- kernel 1a: per-batch sum/sumsq partials ----------------
__global__ void stats_partial(const float* __restrict__ lp, double* __restrict__ part) {
    int blk = blockIdx.x;            // 0..511 = B*32
    int b = blk >> 5, seg = blk & 31;
    const float4* p4 = (const float4*)(lp + (size_t)b * NNL_ + (size_t)seg * (NNL_ / 32));
    double s = 0.0, ss = 0.0;
    for (int idx = threadIdx.x; idx < (NNL_ / 32 / 4); idx += 256) {
        float4 v = p4[idx];
        s  += (double)v.x + (double)v.y + (double)v.z + (double)v.w;
        ss += (double)v.x * v.x + (double)v.y * v.y + (double)v.z * v.z + (double)v.w * v.w;
    }
    __shared__ double sh0[256], sh1[256];
    sh0[threadIdx.x] = s; sh1[threadIdx.x] = ss;
    __syncthreads();
    for (int off = 128; off > 0; off >>= 1) {
        if (threadIdx.x < off) {
            sh0[threadIdx.x] += sh0[threadIdx.x + off];
            sh1[threadIdx.x] += sh1[threadIdx.x + off];
        }
        __syncthreads();
    }
    if (threadIdx.x == 0) { part[blk * 2] = sh0[0]; part[blk * 2 + 1] = sh1[0]; }
}

// ---------------- kernel 1b: finalize mean/invstd ----------------
__global__ void stats_final(const double* __restrict__ part, float* __restrict__ stats) {
    int b = threadIdx.x;
    if (b >= B_) return;
    double s = 0.0, ss = 0.0;
    for (int k = 0; k < 32; ++k) { s += part[(b * 32 + k) * 2]; ss += part[(b * 32 + k) * 2 + 1]; }
    double n = (double)NNL_;
    double mean = s / n;
    double var = (ss - s * s / n) / (n - 1.0);
    stats[b * 2]     = (float)mean;
    stats[b * 2 + 1] = (float)(1.0 / sqrt(var));
}

// ---------------- kernel 2: label-lse -> span potentials ----------------
// One thread per cell; START-major outputs (o = i*N+w); pots in log2 units,
// sbar in nat units (it is E[x], not a log-potential). Formulas r2-verified.
__global__ __launch_bounds__(256)
void pots_kernel(const float* __restrict__ lp, const float* __restrict__ evm,
                 const float* __restrict__ stats, float* __restrict__ W) {
    int t = blockIdx.x * 256 + threadIdx.x;     // 0 .. B*NN-1
    int b = t >> 16;
    int rem = t & (NN_ - 1);
    int i = rem >> 8;
    int w = rem & (N_ - 1);
    if (i + w >= N_) return;
    int j = i + w;
    const float4* xp = (const float4*)(lp  + ((size_t)(b * NN_ + i * N_ + j) << 5));
    const float4* ep = (const float4*)(evm + ((size_t)(b * NN_ + i * N_ + j) << 5));
    float mean = stats[b * 2], invstd = stats[b * 2 + 1];
    float m1 = NEGINF, s1 = 0.f, n1 = 0.f;
    float m2 = NEGINF, s2 = 0.f;
    float m3 = NEGINF, s3 = 0.f;
#pragma unroll
    for (int c = 0; c < 8; ++c) {
        float4 xv = xp[c];
        float4 em = ep[c];
        float x0 = (xv.x - mean) * invstd, x1 = (xv.y - mean) * invstd;
        float x2 = (xv.z - mean) * invstd, x3 = (xv.w - mean) * invstd;
        {
            float cm = fmaxf(fmaxf(x0, x1), fmaxf(x2, x3));
            float nm = fmaxf(m1, cm);
            float sc = __expf(m1 - nm);
            float e0 = __expf(x0 - nm), e1 = __expf(x1 - nm);
            float e2 = __expf(x2 - nm), e3 = __expf(x3 - nm);
            s1 = s1 * sc + (e0 + e1 + e2 + e3);
            n1 = n1 * sc + (e0 * x0 + e1 * x1 + e2 * x2 + e3 * x3);
            m1 = nm;
        }
        {
            float y0 = x0 + __logf(fmaf(em.x, 0.9f, 0.1f) + 1e-10f);
            float y1 = x1 + __logf(fmaf(em.y, 0.9f, 0.1f) + 1e-10f);
            float y2 = x2 + __logf(fmaf(em.z, 0.9f, 0.1f) + 1e-10f);
            float y3 = x3 + __logf(fmaf(em.w, 0.9f, 0.1f) + 1e-10f);
            float cm = fmaxf(fmaxf(y0, y1), fmaxf(y2, y3));
            float nm = fmaxf(m2, cm);
            float sc = __expf(m2 - nm);
            s2 = s2 * sc + __expf(y0 - nm) + __expf(y1 - nm) + __expf(y2 - nm) + __expf(y3 - nm);
            m2 = nm;
        }
        {
            float z0 = fmaf(em.x, 1e6f, x0 - 1e6f);
            float z1 = fmaf(em.y, 1e6f, x1 - 1e6f);
            float z2 = fmaf(em.z, 1e6f, x2 - 1e6f);
            float z3 = fmaf(em.w, 1e6f, x3 - 1e6f);
            float cm = fmaxf(fmaxf(z0, z1), fmaxf(z2, z3));
            float nm = fmaxf(m3, cm);
            float sc = __expf(m3 - nm);
            s3 = s3 * sc + __expf(z0 - nm) + __expf(z1 - nm) + __expf(z2 - nm) + __expf(z3 - nm);
            m3 = nm;
        }
    }
    int o = b * NN_ + i * N_ + w;                // START-major layout
    W[POTS_OFF + 0 * ANN_ + o] = (m1 + __logf(s1)) * LOG2E_F;
    W[POTS_OFF + 1 * ANN_ + o] = n1 / s1;
    W[POTS_OFF + 2 * ANN_ + o] = (m2 + __logf(s2)) * LOG2E_F;
    W[POTS_OFF + 3 * ANN_ + o] = (m3 + __logf(s3)) * LOG2E_F;
}

// ---------------- LDS triangular chart addressing ----------------
// Start-major: row i holds widths u = 0..(255-i), capacity padded to 32-float
// (8-granule) multiples: cap32(i) = 32*(8 - (i>>5)). Total = 36864 floats
// (144 KB). Swizzle: granule index XOR (i&7) — stays in-row because capacity
// is a multiple of 8 granules; keeps 16B alignment for ds_read_b128.
__device__ __forceinline__ int lds_base(int i) {
    int a = i >> 5, c = i & 31;
    // sum_{t<i} 32*(8-(t>>5)) = 1024*(8a - a(a-1)/2) + 32*c*(8-a)
    return ((8 * a - ((a * (a - 1)) >> 1)) << 10) + ((c * (8 - a)) << 5);
}
__device__ __forceinline__ int lds_addr(int i, int u) {
    return lds_base(i) + ((((u >> 2) ^ (i & 7)) << 2) | (u & 3));
}

// unaligned (4B-aligned) 16B global load
__device__ __forceinline__ float4 ld4u(const float* p) {
    float4 v; __builtin_memcpy(&v, p, 16); return v;
}

// ---------------- one width step ----------------
// group = cell (G = 2^LOGG lanes each, consecutive tids). Lane l owns L-granules
// mu = l, l+G, ... (u = 4mu..4mu+3). L-ev (and p0 L-h) are aligned 16B loads;
// R comes from the end-major global row j=i+w: cols c = w-1-u, one unaligned
// 16B load delivers 4 splits reversed (element t <-> c=(w-4-u0)+t <-> u=u0+3-t).
// Only the LAST granule (rem = w-u0 < 4) has masked elements; its R load may
// start up to 3 floats before row j (row j-1 tail, garbage) — masked to
// NEGINF / 0 before use so NaN/Inf garbage cannot propagate.
template <bool EXPM, int LOGG>
__device__ __forceinline__ void stepw(
    float* __restrict__ SL,
    const float* __restrict__ pot, const float* __restrict__ sbr,
    float* __restrict__ EGe, float* __restrict__ EGh, float* __restrict__ SGh,
    const int w, const int cells, const int tid)
{
    constexpr int G = 1 << LOGG;
    const int group = tid >> LOGG;
    const int l = tid & (G - 1);
    if (group >= cells) return;
    const int i = group;
    const int j = i + w;
    const int ib = lds_base(i);
    const int isw = i & 7;
    const float* egE = EGe + j * N_;
    const int W4 = (w + 3) >> 2;
    float m = NEGINF, s = 0.f, n = 0.f;
    for (int mu = l; mu < W4; mu += G) {
        const int u0 = mu << 2;
        const float4 Lv = *(const float4*)&SL[ib + ((mu ^ isw) << 2)];
        const float4 Rv = ld4u(egE + (w - 4 - u0));
        float e0 = Lv.x + Rv.w;      // u=u0   <-> c=w-1-u0
        float e1 = Lv.y + Rv.z;      // u=u0+1
        float e2 = Lv.z + Rv.y;      // u=u0+2
        float e3 = Lv.w + Rv.x;      // u=u0+3
        const int rem = w - u0;      // >=1 always for visited granules
        if (rem < 4) {
            if (rem < 2) e1 = NEGINF;
            if (rem < 3) e2 = NEGINF;
            e3 = NEGINF;
        }
        float cm = fmaxf(fmaxf(e0, e1), fmaxf(e2, e3));
        float nm = fmaxf(m, cm);
        float sc = EX2(m - nm);
        float E0 = EX2(e0 - nm), E1 = EX2(e1 - nm);
        float E2 = EX2(e2 - nm), E3 = EX2(e3 - nm);
        s = s * sc + ((E0 + E1) + (E2 + E3));
        if constexpr (EXPM) {
            const float4 Hl = *(const float4*)(SGh + i * N_ + u0);  // aligned
            const float4 Hr = ld4u(EGh + j * N_ + (w - 4 - u0));
            float h0 = Hl.x + Hr.w, h1 = Hl.y + Hr.z;
            float h2 = Hl.z + Hr.y, h3 = Hl.w + Hr.x;
            if (rem < 4) {           // garbage could be Inf/NaN: 0*Inf = NaN
                if (rem < 2) h1 = 0.f;
                if (rem < 3) h2 = 0.f;
                h3 = 0.f;
            }
            n = n * sc + ((E0 * h0 + E1 * h1) + (E2 * h2 + E3 * h3));
        }
        m = nm;
    }
    // merge across the G lanes of the group (consecutive tids, within a wave)
#pragma unroll
    for (int k = 1; k < G; k <<= 1) {
        float mo = __shfl_xor(m, k);
        float so = __shfl_xor(s, k);
        float no = 0.f;
        if constexpr (EXPM) no = __shfl_xor(n, k);
        float nm = fmaxf(m, mo);
        float a  = EX2(m - nm), bb = EX2(mo - nm);
        s = s * a + so * bb;
        if constexpr (EXPM) n = n * a + no * bb;
        m = nm;
    }
    if (l == 0) {
        float v = pot[i * N_ + w] + m + LG2(s);
        SL[lds_addr(i, w)] = v;
        EGe[j * N_ + w] = v;
        if constexpr (EXPM) {
            float hv = sbr[i * N_ + w] + n / s;
            SGh[i * N_ + w] = hv;
            EGh[j * N_ + w] = hv;
        }
    }
}

template <bool EXPM>
__device__ __forceinline__ void cky_loop(
    float* __restrict__ SL,
    const float* __restrict__ pot, const float* __restrict__ sbr,
    float* __restrict__ EGe, float* __restrict__ EGh, float* __restrict__ SGh,
    const int len, const int tid)
{
    // width-0 diagonal
    for (int i = tid; i < len; i += 1024) {
        float v = pot[i * N_];
        SL[lds_addr(i, 0)] = v;
        EGe[i * N_] = v;
        if constexpr (EXPM) { float h0 = sbr[i * N_]; SGh[i * N_] = h0; EGh[i * N_] = h0; }
    }
    __syncthreads();
    for (int w = 1; w < len; ++w) {
        const int cells = len - w;
        if (cells > 128)      stepw<EXPM, 2>(SL, pot, sbr, EGe, EGh, SGh, w, cells, tid);
        else if (cells > 64)  stepw<EXPM, 3>(SL, pot, sbr, EGe, EGh, SGh, w, cells, tid);
        else if (cells > 32)  stepw<EXPM, 4>(SL, pot, sbr, EGe, EGh, SGh, w, cells, tid);
        else if (cells > 16)  stepw<EXPM, 5>(SL, pot, sbr, EGe, EGh, SGh, w, cells, tid);
        else                  stepw<EXPM, 6>(SL, pot, sbr, EGe, EGh, SGh, w, cells, tid);
        __syncthreads();
    }
}

// ---------------- kernel 3: all three CKY inside passes ----------------
__global__ __launch_bounds__(1024, 1)
void cky_all(float* __restrict__ W, const int* __restrict__ lengths) {
    __shared__ float SL[36864];           // 144 KB triangular chart
    const int bx = blockIdx.x;
    const int p = bx >> 4, b = bx & 15;
    const int tid = threadIdx.x;
    int len = lengths[b];
    if (len < 1) len = 1;
    if (len > N_) len = N_;
    float* zres = W + POTS_OFF + 9 * ANN_;

    if (p == 0) {
        const float* pot = W + POTS_OFF + 0 * ANN_ + b * NN_;
        const float* sbr = W + POTS_OFF + 1 * ANN_ + b * NN_;
        float* EGe = W + POTS_OFF + 4 * ANN_ + b * NN_;
        float* EGh = W + POTS_OFF + 5 * ANN_ + b * NN_;
        float* SGh = W + POTS_OFF + 6 * ANN_ + b * NN_;
        cky_loop<true>(SL, pot, sbr, EGe, EGh, SGh, len, tid);
        if (tid == 0) {
            zres[b]      = SL[lds_addr(0, len - 1)];   // logZ_full (log2 units)
            zres[48 + b] = SGh[len - 1];               // E[sum sbar] (nat units)
        }
    } else {
        const float* pot = W + POTS_OFF + (p == 1 ? 2 : 3) * ANN_ + b * NN_;
        float* EGe = W + POTS_OFF + (p == 1 ? 7 : 8) * ANN_ + b * NN_;
        cky_loop<false>(SL, pot, nullptr, EGe, nullptr, nullptr, len, tid);
        if (tid == 0) zres[p * 16 + b] = SL[lds_addr(0, len - 1)];
    }
}

// ---------------- kernel 4: combine outputs ----------------
__global__ void combine_kernel(const float* __restrict__ W, float* __restrict__ out) {
    int b = threadIdx.x;
    if (b >= B_) return;
    const float* zres = W + POTS_OFF + 9 * ANN_;
    float zf = zres[b], zs = zres[16 + b], zp = zres[32 + b], hr = zres[48 + b];
    out[b]          = (zp - zf) * LN2_F;   // log_prob
    out[16 + b]     = (zs - zf) * LN2_F;   // log_prob_smooth
    out[32 + b]     = zf * LN2_F - hr;     // entropy = z_full - E[sum sbar]
}

extern "C" void kernel_launch(void* const* d_in, const int* in_sizes, int n_in,
                              void* d_out, int out_size, void* d_ws, size_t ws_size,
                              hipStream_t stream) {
    const float* lp      = (const float*)d_in[0];
    // d_in[1] (mask) is unused by the reference
    const int*   lengths = (const int*)d_in[2];
    const float* evm     = (const float*)d_in[3];
    float*  W    = (float*)d_ws;
    double* part = (double*)d_ws;
    float*  stats = W + 2048;
    float*  out  = (float*)d_out;

    stats_partial<<<B_ * 32, 256, 0, stream>>>(lp, part);
    stats_final<<<1, 64, 0, stream>>>(part, stats);
    pots_kernel<<<(B_ * NN_) / 256, 256, 0, stream>>>(lp, evm, stats, W);
    cky_all<<<3 * B_, 1024, 0, stream>>>(W, lengths);
    combine_kernel<<<1, 64, 0, stream>>>(W, out);
}